// Round 5
// baseline (100.628 us; speedup 1.0000x reference)
//
#include <hip/hip_runtime.h>
#include <hip/hip_bf16.h>

typedef short short8 __attribute__((ext_vector_type(8)));
typedef float floatx4 __attribute__((ext_vector_type(4)));
typedef float floatx16 __attribute__((ext_vector_type(16)));

#define HID 32
#define NTD 8
#define FAN_IN 18

// round-to-nearest-even f32 -> bf16 (bit pattern in a short)
__device__ __forceinline__ short f2bf(float f) {
    union { float f; unsigned u; } v; v.f = f;
    unsigned r = v.u + 0x7fffu + ((v.u >> 16) & 1u);
    return (short)(r >> 16);
}

// sigmoid via hw exp2 + hw rcp
__device__ __forceinline__ float fast_sigmoid(float x) {
    float e = __builtin_amdgcn_exp2f(x * -1.44269504f);
    return __builtin_amdgcn_rcpf(1.0f + e);
}

// ---------------- table build: T[n] = 32B row: [emb(8) | mask, 1.0, 0x6] as bf16
__global__ void build_table(const float* __restrict__ emb,
                            const float* __restrict__ mask,
                            short* __restrict__ T, int N) {
    int n = blockIdx.x * blockDim.x + threadIdx.x;
    if (n >= N) return;
    const float4* p = (const float4*)(emb + (size_t)n * NTD);
    float4 lo = p[0], hi = p[1];
    short8 a, b;
    a[0] = f2bf(lo.x); a[1] = f2bf(lo.y); a[2] = f2bf(lo.z); a[3] = f2bf(lo.w);
    a[4] = f2bf(hi.x); a[5] = f2bf(hi.y); a[6] = f2bf(hi.z); a[7] = f2bf(hi.w);
    b[0] = f2bf(mask[n]); b[1] = (short)0x3F80;  // 1.0 bf16 (bias carrier)
    b[2] = b[3] = b[4] = b[5] = b[6] = b[7] = 0;
    short8* row = (short8*)(T + (size_t)n * 16);
    row[0] = a; row[1] = b;
}

// ---------------- main kernel (32x32x16 MFMA, 64 edges / iteration) ----------------
struct IdxQ { unsigned sA, dA, sB, dB; };

// streaming (non-temporal) index loads: keep the 100MB index stream out of L1/L2 LRU
template <int ESZ>
__device__ __forceinline__ IdxQ load_idx(const char* __restrict__ sBase,
                                         const char* __restrict__ dBase,
                                         unsigned grp, unsigned nGroups,
                                         unsigned E, unsigned c) {
    unsigned g = grp < nGroups ? grp : nGroups - 1u;   // clamp (prefetch safety)
    unsigned eA = g * 64u + c;
    unsigned eB = eA + 32u;
    if (eA >= E) eA = E - 1u;
    if (eB >= E) eB = E - 1u;
    IdxQ q;
    q.sA = __builtin_nontemporal_load((const unsigned*)(sBase + (size_t)eA * ESZ));
    q.dA = __builtin_nontemporal_load((const unsigned*)(dBase + (size_t)eA * ESZ));
    q.sB = __builtin_nontemporal_load((const unsigned*)(sBase + (size_t)eB * ESZ));
    q.dB = __builtin_nontemporal_load((const unsigned*)(dBase + (size_t)eB * ESZ));
    return q;
}

// table gathers: NORMAL caching (we want these L2-resident)
__device__ __forceinline__ short8 g16(const char* __restrict__ Tc, unsigned idx, unsigned hoff) {
    return *(const short8*)(Tc + (idx * 32u + hoff));
}

template <int ESZ>
__device__ void run32(const char* __restrict__ ei,
                      const char* __restrict__ Tc,
                      float* __restrict__ out, unsigned E,
                      short8 as, short8 ad, const float* __restrict__ w2r, float bias2,
                      unsigned waveId, unsigned nWaves, int h, int c, int lane) {
    const unsigned nGroups = (E + 63u) >> 6;
    const char* sBase = ei;
    const char* dBase = ei + (size_t)E * ESZ;
    const unsigned hoff = (unsigned)h * 16u;

    if (waveId >= nGroups) return;

    unsigned cur = waveId;

    // prologue: frags for cur; indices prefetched for cur+W and cur+2W (depth 3)
    IdxQ i0 = load_idx<ESZ>(sBase, dBase, cur, nGroups, E, (unsigned)c);
    short8 bsA = g16(Tc, i0.sA, hoff);
    short8 bdA = g16(Tc, i0.dA, hoff);
    short8 bsB = g16(Tc, i0.sB, hoff);
    short8 bdB = g16(Tc, i0.dB, hoff);
    IdxQ iN1 = load_idx<ESZ>(sBase, dBase, cur + nWaves, nGroups, E, (unsigned)c);
    IdxQ iN2 = load_idx<ESZ>(sBase, dBase, cur + 2u * nWaves, nGroups, E, (unsigned)c);

    while (true) {
        // gathers for group cur+W (indices iN1: issued 2 iterations ago -> complete)
        short8 nsA = g16(Tc, iN1.sA, hoff);
        short8 ndA = g16(Tc, iN1.dA, hoff);
        short8 nsB = g16(Tc, iN1.sB, hoff);
        short8 ndB = g16(Tc, iN1.dB, hoff);
        // index prefetch for group cur+3W (2 full iterations of slack)
        IdxQ iN3 = load_idx<ESZ>(sBase, dBase, cur + 3u * nWaves, nGroups, E, (unsigned)c);

        // ---- layer 1: two 32-edge tiles, 2 MFMAs each (s-half K + d-half K) ----
        floatx16 accA = {0.f,0.f,0.f,0.f,0.f,0.f,0.f,0.f,0.f,0.f,0.f,0.f,0.f,0.f,0.f,0.f};
        floatx16 accB = accA;
        accA = __builtin_amdgcn_mfma_f32_32x32x16_bf16(as, bsA, accA, 0, 0, 0);
        accB = __builtin_amdgcn_mfma_f32_32x32x16_bf16(as, bsB, accB, 0, 0, 0);
        accA = __builtin_amdgcn_mfma_f32_32x32x16_bf16(ad, bdA, accA, 0, 0, 0);
        accB = __builtin_amdgcn_mfma_f32_32x32x16_bf16(ad, bdB, accB, 0, 0, 0);

        // ---- layer 2: lane(h,c) holds H rows (q&3)+8*(q>>2)+4h of its edge ----
        float pA0 = 0.f, pA1 = 0.f, pB0 = 0.f, pB1 = 0.f;
        #pragma unroll
        for (int q = 0; q < 16; q += 2) {
            pA0 += fmaxf(accA[q],     0.f) * w2r[q];
            pA1 += fmaxf(accA[q + 1], 0.f) * w2r[q + 1];
            pB0 += fmaxf(accB[q],     0.f) * w2r[q];
            pB1 += fmaxf(accB[q + 1], 0.f) * w2r[q + 1];
        }
        float pA = pA0 + pA1;
        float pB = pB0 + pB1;
        pA += __shfl_xor(pA, 32, 64);   // combine the two h-halves (rows 0..31 complete)
        pB += __shfl_xor(pB, 32, 64);
        float vA = fast_sigmoid(pA + bias2);
        float vB = fast_sigmoid(pB + bias2);

        // lane l stores edge base64 + l; streaming store (no reuse)
        float v = (h == 0) ? vA : vB;
        unsigned e = (cur << 6) + (unsigned)lane;
        if (e < E) __builtin_nontemporal_store(v, out + e);

        cur += nWaves;
        if (cur >= nGroups) break;
        bsA = nsA; bdA = ndA; bsB = nsB; bdB = ndB;
        iN1 = iN2;
        iN2 = iN3;
    }
}

__global__ __launch_bounds__(256, 6) void lg_table_kernel(
    const char* __restrict__ ei_bytes,
    const short* __restrict__ T,
    const float* __restrict__ W1,
    const float* __restrict__ b1,
    const float* __restrict__ W2,
    const float* __restrict__ b2,
    float* __restrict__ out,
    long long E)
{
    const int lane = threadIdx.x & 63;
    const int waveInBlock = threadIdx.x >> 6;
    const unsigned waveId = (unsigned)(blockIdx.x * (blockDim.x >> 6) + waveInBlock);
    const unsigned nWaves = (unsigned)(gridDim.x * (blockDim.x >> 6));

    // detect edge_index element size: int64 (odd 4B words all zero) vs int32
    const int* ei32 = (const int*)ei_bytes;
    int probe = ei32[2 * lane + 1];
    unsigned long long nz = __ballot(probe != 0);
    const int esz = (nz == 0ull) ? 8 : 4;

    const int c = lane & 31;   // B col / A row index
    const int h = lane >> 5;   // k-half: k = 8h + j

    // A fragments (32x32x16): A[row=c][k=8h+j]
    // s-MFMA: k0..7 = W1 rows 0..7 (emb_s), k8 = W1 row 16 (mask_s), k9 = b1, k10..15 = 0
    // d-MFMA: k0..7 = W1 rows 8..15 (emb_d), k8 = W1 row 17 (mask_d), k9..15 = 0
    short8 as, ad;
    #pragma unroll
    for (int j = 0; j < 8; ++j) {
        float vs = 0.f, vd = 0.f;
        if (h == 0) {
            vs = W1[j * HID + c];
            vd = W1[(8 + j) * HID + c];
        } else {
            if (j == 0) { vs = W1[16 * HID + c]; vd = W1[17 * HID + c]; }
            else if (j == 1) { vs = b1[c]; }
        }
        as[j] = f2bf(vs);
        ad[j] = f2bf(vd);
    }

    // W2 for the 16 H-rows this lane's acc regs hold: row(q) = (q&3) + 8*(q>>2) + 4h
    float w2r[16];
    #pragma unroll
    for (int q = 0; q < 16; ++q)
        w2r[q] = W2[(q & 3) + 8 * (q >> 2) + 4 * h];

    const float bias2 = b2[0];

    if (esz == 8)
        run32<8>(ei_bytes, (const char*)T, out, (unsigned)E, as, ad, w2r, bias2,
                 waveId, nWaves, h, c, lane);
    else
        run32<4>(ei_bytes, (const char*)T, out, (unsigned)E, as, ad, w2r, bias2,
                 waveId, nWaves, h, c, lane);
}

// ---------------- fallback (round-1 kernel, used if d_ws too small) ----------------
__global__ __launch_bounds__(256, 4) void lg_kernel(
    const float* __restrict__ nt_emb,
    const char* __restrict__ ei_bytes,
    const float* __restrict__ lm_mask,
    const float* __restrict__ W1,
    const float* __restrict__ b1,
    const float* __restrict__ W2,
    const float* __restrict__ b2,
    float* __restrict__ out,
    long long E)
{
    const int lane = threadIdx.x & 63;
    const int waveInBlock = threadIdx.x >> 6;
    const long long waveId = (long long)blockIdx.x * (blockDim.x >> 6) + waveInBlock;
    const long long nWaves = (long long)gridDim.x * (blockDim.x >> 6);

    const int* ei32 = (const int*)ei_bytes;
    int probe = ei32[2 * lane + 1];
    unsigned long long nz = __ballot(probe != 0);
    const long long esz = (nz == 0ull) ? 8 : 4;

    const int r = lane & 15;
    const int g = lane >> 4;

    short8 a0, a1;
    #pragma unroll
    for (int j = 0; j < 8; ++j) {
        int k = g * 8 + j;
        float v0 = 0.f, v1 = 0.f;
        if (k < FAN_IN)       { v0 = W1[k * HID + r];      v1 = W1[k * HID + 16 + r]; }
        else if (k == FAN_IN) { v0 = b1[r];                v1 = b1[16 + r]; }
        a0[j] = f2bf(v0);
        a1[j] = f2bf(v1);
    }

    float w2v0[4], w2v1[4];
    #pragma unroll
    for (int q = 0; q < 4; ++q) {
        w2v0[q] = W2[g * 4 + q];
        w2v1[q] = W2[16 + g * 4 + q];
    }
    const float bias2 = b2[0];

    const long long nGroups = (E + 15) >> 4;
    for (long long grp = waveId; grp < nGroups; grp += nWaves) {
        long long e = (grp << 4) + r;
        const bool valid = (e < E);
        long long ec = valid ? e : (E - 1);

        int s = *(const int*)(ei_bytes + ec * esz);
        int d = *(const int*)(ei_bytes + (E + ec) * esz);

        short8 fb;
        #pragma unroll
        for (int j = 0; j < 8; ++j) fb[j] = 0;
        if (g < 2) {
            const float4* p = (const float4*)(nt_emb + (long long)(g == 0 ? s : d) * NTD);
            float4 lo = p[0];
            float4 hi = p[1];
            fb[0] = f2bf(lo.x); fb[1] = f2bf(lo.y); fb[2] = f2bf(lo.z); fb[3] = f2bf(lo.w);
            fb[4] = f2bf(hi.x); fb[5] = f2bf(hi.y); fb[6] = f2bf(hi.z); fb[7] = f2bf(hi.w);
        } else if (g == 2) {
            fb[0] = f2bf(lm_mask[s]);
            fb[1] = f2bf(lm_mask[d]);
            fb[2] = (short)0x3F80;
        }

        floatx4 acc0 = {0.f, 0.f, 0.f, 0.f};
        floatx4 acc1 = {0.f, 0.f, 0.f, 0.f};
        acc0 = __builtin_amdgcn_mfma_f32_16x16x32_bf16(a0, fb, acc0, 0, 0, 0);
        acc1 = __builtin_amdgcn_mfma_f32_16x16x32_bf16(a1, fb, acc1, 0, 0, 0);

        float partial = 0.f;
        #pragma unroll
        for (int q = 0; q < 4; ++q) {
            partial += fmaxf(acc0[q], 0.f) * w2v0[q];
            partial += fmaxf(acc1[q], 0.f) * w2v1[q];
        }
        partial += __shfl_xor(partial, 16, 64);
        partial += __shfl_xor(partial, 32, 64);

        float val = fast_sigmoid(partial + bias2);
        if (g == 0 && valid) out[e] = val;
    }
}

extern "C" void kernel_launch(void* const* d_in, const int* in_sizes, int n_in,
                              void* d_out, int out_size, void* d_ws, size_t ws_size,
                              hipStream_t stream) {
    const float* nt_emb = (const float*)d_in[0];
    const char*  ei     = (const char*)d_in[1];
    const float* lm     = (const float*)d_in[2];
    const float* W1     = (const float*)d_in[3];
    const float* b1     = (const float*)d_in[4];
    const float* W2     = (const float*)d_in[5];
    const float* b2     = (const float*)d_in[6];
    float* out = (float*)d_out;

    long long E = (long long)in_sizes[1] / 2;   // edge_index is [2, E]
    int N = in_sizes[2];                        // lm_mask is [N]

    size_t tableBytes = (size_t)N * 32;
    if (ws_size >= tableBytes) {
        short* T = (short*)d_ws;
        build_table<<<dim3((N + 255) / 256), dim3(256), 0, stream>>>(nt_emb, lm, T, N);
        lg_table_kernel<<<dim3(2048), dim3(256), 0, stream>>>(ei, T, W1, b1, W2, b2, out, E);
    } else {
        lg_kernel<<<dim3(2048), dim3(256), 0, stream>>>(nt_emb, ei, lm, W1, b1, W2, b2, out, E);
    }
}

// Round 6
// 83.277 us; speedup vs baseline: 1.2083x; 1.2083x over previous
//
#include <hip/hip_runtime.h>
#include <hip/hip_bf16.h>

typedef short short8 __attribute__((ext_vector_type(8)));
typedef float floatx4 __attribute__((ext_vector_type(4)));
typedef float floatx16 __attribute__((ext_vector_type(16)));

#define HID 32
#define NTD 8
#define FAN_IN 18

// round-to-nearest-even f32 -> bf16 (bit pattern in a short)
__device__ __forceinline__ short f2bf(float f) {
    union { float f; unsigned u; } v; v.f = f;
    unsigned r = v.u + 0x7fffu + ((v.u >> 16) & 1u);
    return (short)(r >> 16);
}

// sigmoid via hw exp2 + hw rcp
__device__ __forceinline__ float fast_sigmoid(float x) {
    float e = __builtin_amdgcn_exp2f(x * -1.44269504f);
    return __builtin_amdgcn_rcpf(1.0f + e);
}

// ---------------- table build: T[n] = 32B row: [emb(8) | mask, 1.0, 0x6] as bf16
__global__ void build_table(const float* __restrict__ emb,
                            const float* __restrict__ mask,
                            short* __restrict__ T, int N) {
    int n = blockIdx.x * blockDim.x + threadIdx.x;
    if (n >= N) return;
    const float4* p = (const float4*)(emb + (size_t)n * NTD);
    float4 lo = p[0], hi = p[1];
    short8 a, b;
    a[0] = f2bf(lo.x); a[1] = f2bf(lo.y); a[2] = f2bf(lo.z); a[3] = f2bf(lo.w);
    a[4] = f2bf(hi.x); a[5] = f2bf(hi.y); a[6] = f2bf(hi.z); a[7] = f2bf(hi.w);
    b[0] = f2bf(mask[n]); b[1] = (short)0x3F80;  // 1.0 bf16 (bias carrier)
    b[2] = b[3] = b[4] = b[5] = b[6] = b[7] = 0;
    short8* row = (short8*)(T + (size_t)n * 16);
    row[0] = a; row[1] = b;
}

// ---------------- main kernel (32x32x16 MFMA, 64 edges / iteration) ----------------
// Gather scheme: lane c (<32) owns the FULL 32B s-row of edge c; lane 32+c owns the
// full d-row of edge c. Both 16B halves come from the same 64B line & same lane ->
// one L2 request per node reference (2 per edge, the structural minimum).
// Fragments are rebuilt with a lane<->lane+32 half-exchange:
//   vA = {S_lo | D_lo}, vB = {S_hi | D_hi}   (lo lanes | hi lanes)
//   s-frag = {vA | shfl32(vB)}, d-frag = {shfl32(vA) | vB}

__device__ __forceinline__ void make_frags(int4 lo, int4 hi, int h,
                                           short8& sf, short8& df) {
    int4 s4, d4;
    #pragma unroll
    for (int j = 0; j < 4; ++j) {
        int a = (&lo.x)[j];
        int b = (&hi.x)[j];
        int as = __shfl_xor(a, 32, 64);
        int bs = __shfl_xor(b, 32, 64);
        (&s4.x)[j] = h ? bs : a;
        (&d4.x)[j] = h ? b : as;
    }
    sf = __builtin_bit_cast(short8, s4);
    df = __builtin_bit_cast(short8, d4);
}

template <int ESZ>
__device__ __forceinline__ unsigned ld_idx(const char* __restrict__ idxBase,
                                           unsigned grp, unsigned nGroups,
                                           unsigned E, unsigned off, unsigned cc) {
    unsigned g = grp < nGroups ? grp : nGroups - 1u;   // clamp (prefetch safety)
    unsigned e = g * 64u + off + cc;
    if (e >= E) e = E - 1u;
    return *(const unsigned*)(idxBase + (size_t)e * ESZ);
}

template <int ESZ>
__device__ void run32(const char* __restrict__ ei,
                      const char* __restrict__ Tc,
                      float* __restrict__ out, unsigned E,
                      short8 as, short8 ad, const float* __restrict__ w2r, float bias2,
                      unsigned waveId, unsigned nWaves, int h, int c, int lane) {
    const unsigned nGroups = (E + 63u) >> 6;
    // lanes<32 read the s-index stream, lanes>=32 the d-index stream
    const char* idxBase = ei + (h ? (size_t)E * ESZ : 0);
    const unsigned cc = (unsigned)c;

    if (waveId >= nGroups) return;
    unsigned cur = waveId;

    // prologue: indices+rows for cur; indices for cur+W
    unsigned iA = ld_idx<ESZ>(idxBase, cur, nGroups, E, 0u, cc);
    unsigned iB = ld_idx<ESZ>(idxBase, cur, nGroups, E, 32u, cc);
    int4 loA = *(const int4*)(Tc + iA * 32u);
    int4 hiA = *(const int4*)(Tc + iA * 32u + 16u);
    int4 loB = *(const int4*)(Tc + iB * 32u);
    int4 hiB = *(const int4*)(Tc + iB * 32u + 16u);
    unsigned nA = ld_idx<ESZ>(idxBase, cur + nWaves, nGroups, E, 0u, cc);
    unsigned nB = ld_idx<ESZ>(idxBase, cur + nWaves, nGroups, E, 32u, cc);

    while (true) {
        // --- prefetch: next group's rows + next-next indices (overlap compute) ---
        int4 nloA = *(const int4*)(Tc + nA * 32u);
        int4 nhiA = *(const int4*)(Tc + nA * 32u + 16u);
        int4 nloB = *(const int4*)(Tc + nB * 32u);
        int4 nhiB = *(const int4*)(Tc + nB * 32u + 16u);
        unsigned nnA = ld_idx<ESZ>(idxBase, cur + 2u * nWaves, nGroups, E, 0u, cc);
        unsigned nnB = ld_idx<ESZ>(idxBase, cur + 2u * nWaves, nGroups, E, 32u, cc);

        // --- fragment build (lane+-32 half exchange) ---
        short8 sfA, dfA, sfB, dfB;
        make_frags(loA, hiA, h, sfA, dfA);
        make_frags(loB, hiB, h, sfB, dfB);

        // ---- layer 1: two 32-edge tiles, 2 MFMAs each (s-half K + d-half K) ----
        floatx16 accA = {0.f,0.f,0.f,0.f,0.f,0.f,0.f,0.f,0.f,0.f,0.f,0.f,0.f,0.f,0.f,0.f};
        floatx16 accB = accA;
        accA = __builtin_amdgcn_mfma_f32_32x32x16_bf16(as, sfA, accA, 0, 0, 0);
        accB = __builtin_amdgcn_mfma_f32_32x32x16_bf16(as, sfB, accB, 0, 0, 0);
        accA = __builtin_amdgcn_mfma_f32_32x32x16_bf16(ad, dfA, accA, 0, 0, 0);
        accB = __builtin_amdgcn_mfma_f32_32x32x16_bf16(ad, dfB, accB, 0, 0, 0);

        // ---- layer 2: lane(h,c) holds H rows (q&3)+8*(q>>2)+4h of its edge ----
        float pA0 = 0.f, pA1 = 0.f, pB0 = 0.f, pB1 = 0.f;
        #pragma unroll
        for (int q = 0; q < 16; q += 2) {
            pA0 += fmaxf(accA[q],     0.f) * w2r[q];
            pA1 += fmaxf(accA[q + 1], 0.f) * w2r[q + 1];
            pB0 += fmaxf(accB[q],     0.f) * w2r[q];
            pB1 += fmaxf(accB[q + 1], 0.f) * w2r[q + 1];
        }
        float pA = pA0 + pA1;
        float pB = pB0 + pB1;
        pA += __shfl_xor(pA, 32, 64);   // combine the two h-halves
        pB += __shfl_xor(pB, 32, 64);
        float vA = fast_sigmoid(pA + bias2);
        float vB = fast_sigmoid(pB + bias2);

        // lane l stores edge base64 + l
        float v = (h == 0) ? vA : vB;
        unsigned e = (cur << 6) + (unsigned)lane;
        if (e < E) out[e] = v;

        cur += nWaves;
        if (cur >= nGroups) break;
        loA = nloA; hiA = nhiA; loB = nloB; hiB = nhiB;
        nA = nnA; nB = nnB;
    }
}

__global__ __launch_bounds__(256, 4) void lg_table_kernel(
    const char* __restrict__ ei_bytes,
    const short* __restrict__ T,
    const float* __restrict__ W1,
    const float* __restrict__ b1,
    const float* __restrict__ W2,
    const float* __restrict__ b2,
    float* __restrict__ out,
    long long E)
{
    const int lane = threadIdx.x & 63;
    const int waveInBlock = threadIdx.x >> 6;
    const unsigned waveId = (unsigned)(blockIdx.x * (blockDim.x >> 6) + waveInBlock);
    const unsigned nWaves = (unsigned)(gridDim.x * (blockDim.x >> 6));

    // detect edge_index element size: int64 (odd 4B words all zero) vs int32
    const int* ei32 = (const int*)ei_bytes;
    int probe = ei32[2 * lane + 1];
    unsigned long long nz = __ballot(probe != 0);
    const int esz = (nz == 0ull) ? 8 : 4;

    const int c = lane & 31;   // B col / A row index
    const int h = lane >> 5;   // k-half: k = 8h + j

    // A fragments (32x32x16): A[row=c][k=8h+j]
    // s-MFMA: k0..7 = W1 rows 0..7 (emb_s), k8 = W1 row 16 (mask_s), k9 = b1, k10..15 = 0
    // d-MFMA: k0..7 = W1 rows 8..15 (emb_d), k8 = W1 row 17 (mask_d), k9..15 = 0
    short8 as, ad;
    #pragma unroll
    for (int j = 0; j < 8; ++j) {
        float vs = 0.f, vd = 0.f;
        if (h == 0) {
            vs = W1[j * HID + c];
            vd = W1[(8 + j) * HID + c];
        } else {
            if (j == 0) { vs = W1[16 * HID + c]; vd = W1[17 * HID + c]; }
            else if (j == 1) { vs = b1[c]; }
        }
        as[j] = f2bf(vs);
        ad[j] = f2bf(vd);
    }

    // W2 for the 16 H-rows this lane's acc regs hold: row(q) = (q&3) + 8*(q>>2) + 4h
    float w2r[16];
    #pragma unroll
    for (int q = 0; q < 16; ++q)
        w2r[q] = W2[(q & 3) + 8 * (q >> 2) + 4 * h];

    const float bias2 = b2[0];

    if (esz == 8)
        run32<8>(ei_bytes, (const char*)T, out, (unsigned)E, as, ad, w2r, bias2,
                 waveId, nWaves, h, c, lane);
    else
        run32<4>(ei_bytes, (const char*)T, out, (unsigned)E, as, ad, w2r, bias2,
                 waveId, nWaves, h, c, lane);
}

// ---------------- fallback (round-1 kernel, used if d_ws too small) ----------------
__global__ __launch_bounds__(256, 4) void lg_kernel(
    const float* __restrict__ nt_emb,
    const char* __restrict__ ei_bytes,
    const float* __restrict__ lm_mask,
    const float* __restrict__ W1,
    const float* __restrict__ b1,
    const float* __restrict__ W2,
    const float* __restrict__ b2,
    float* __restrict__ out,
    long long E)
{
    const int lane = threadIdx.x & 63;
    const int waveInBlock = threadIdx.x >> 6;
    const long long waveId = (long long)blockIdx.x * (blockDim.x >> 6) + waveInBlock;
    const long long nWaves = (long long)gridDim.x * (blockDim.x >> 6);

    const int* ei32 = (const int*)ei_bytes;
    int probe = ei32[2 * lane + 1];
    unsigned long long nz = __ballot(probe != 0);
    const long long esz = (nz == 0ull) ? 8 : 4;

    const int r = lane & 15;
    const int g = lane >> 4;

    short8 a0, a1;
    #pragma unroll
    for (int j = 0; j < 8; ++j) {
        int k = g * 8 + j;
        float v0 = 0.f, v1 = 0.f;
        if (k < FAN_IN)       { v0 = W1[k * HID + r];      v1 = W1[k * HID + 16 + r]; }
        else if (k == FAN_IN) { v0 = b1[r];                v1 = b1[16 + r]; }
        a0[j] = f2bf(v0);
        a1[j] = f2bf(v1);
    }

    float w2v0[4], w2v1[4];
    #pragma unroll
    for (int q = 0; q < 4; ++q) {
        w2v0[q] = W2[g * 4 + q];
        w2v1[q] = W2[16 + g * 4 + q];
    }
    const float bias2 = b2[0];

    const long long nGroups = (E + 15) >> 4;
    for (long long grp = waveId; grp < nGroups; grp += nWaves) {
        long long e = (grp << 4) + r;
        const bool valid = (e < E);
        long long ec = valid ? e : (E - 1);

        int s = *(const int*)(ei_bytes + ec * esz);
        int d = *(const int*)(ei_bytes + (E + ec) * esz);

        short8 fb;
        #pragma unroll
        for (int j = 0; j < 8; ++j) fb[j] = 0;
        if (g < 2) {
            const float4* p = (const float4*)(nt_emb + (long long)(g == 0 ? s : d) * NTD);
            float4 lo = p[0];
            float4 hi = p[1];
            fb[0] = f2bf(lo.x); fb[1] = f2bf(lo.y); fb[2] = f2bf(lo.z); fb[3] = f2bf(lo.w);
            fb[4] = f2bf(hi.x); fb[5] = f2bf(hi.y); fb[6] = f2bf(hi.z); fb[7] = f2bf(hi.w);
        } else if (g == 2) {
            fb[0] = f2bf(lm_mask[s]);
            fb[1] = f2bf(lm_mask[d]);
            fb[2] = (short)0x3F80;
        }

        floatx4 acc0 = {0.f, 0.f, 0.f, 0.f};
        floatx4 acc1 = {0.f, 0.f, 0.f, 0.f};
        acc0 = __builtin_amdgcn_mfma_f32_16x16x32_bf16(a0, fb, acc0, 0, 0, 0);
        acc1 = __builtin_amdgcn_mfma_f32_16x16x32_bf16(a1, fb, acc1, 0, 0, 0);

        float partial = 0.f;
        #pragma unroll
        for (int q = 0; q < 4; ++q) {
            partial += fmaxf(acc0[q], 0.f) * w2v0[q];
            partial += fmaxf(acc1[q], 0.f) * w2v1[q];
        }
        partial += __shfl_xor(partial, 16, 64);
        partial += __shfl_xor(partial, 32, 64);

        float val = fast_sigmoid(partial + bias2);
        if (g == 0 && valid) out[e] = val;
    }
}

extern "C" void kernel_launch(void* const* d_in, const int* in_sizes, int n_in,
                              void* d_out, int out_size, void* d_ws, size_t ws_size,
                              hipStream_t stream) {
    const float* nt_emb = (const float*)d_in[0];
    const char*  ei     = (const char*)d_in[1];
    const float* lm     = (const float*)d_in[2];
    const float* W1     = (const float*)d_in[3];
    const float* b1     = (const float*)d_in[4];
    const float* W2     = (const float*)d_in[5];
    const float* b2     = (const float*)d_in[6];
    float* out = (float*)d_out;

    long long E = (long long)in_sizes[1] / 2;   // edge_index is [2, E]
    int N = in_sizes[2];                        // lm_mask is [N]

    size_t tableBytes = (size_t)N * 32;
    if (ws_size >= tableBytes) {
        short* T = (short*)d_ws;
        build_table<<<dim3((N + 255) / 256), dim3(256), 0, stream>>>(nt_emb, lm, T, N);
        lg_table_kernel<<<dim3(2048), dim3(256), 0, stream>>>(ei, T, W1, b1, W2, b2, out, E);
    } else {
        lg_kernel<<<dim3(2048), dim3(256), 0, stream>>>(nt_emb, ei, lm, W1, b1, W2, b2, out, E);
    }
}

// Round 7
// 74.433 us; speedup vs baseline: 1.3519x; 1.1188x over previous
//
#include <hip/hip_runtime.h>
#include <hip/hip_bf16.h>

typedef short short8 __attribute__((ext_vector_type(8)));
typedef float floatx4 __attribute__((ext_vector_type(4)));
typedef float floatx16 __attribute__((ext_vector_type(16)));

#define HID 32
#define NTD 8
#define FAN_IN 18

// round-to-nearest-even f32 -> bf16 (bit pattern in a short)
__device__ __forceinline__ short f2bf(float f) {
    union { float f; unsigned u; } v; v.f = f;
    unsigned r = v.u + 0x7fffu + ((v.u >> 16) & 1u);
    return (short)(r >> 16);
}

// f32 -> bf16 with LSB stolen: RNE at bit 17, LSB carries one mask bit
__device__ __forceinline__ unsigned short pack_emb(float f, unsigned bit) {
    union { float f; unsigned u; } v; v.f = f;
    unsigned r = v.u + 0xFFFFu + ((v.u >> 17) & 1u);
    unsigned short s = (unsigned short)((r >> 16) & 0xFFFEu);
    return (unsigned short)(s | bit);
}

// sigmoid via hw exp2 + hw rcp
__device__ __forceinline__ float fast_sigmoid(float x) {
    float e = __builtin_amdgcn_exp2f(x * -1.44269504f);
    return __builtin_amdgcn_rcpf(1.0f + e);
}

// ---------------- table build: T[n] = 16B row: 8 bf16 emb, LSBs = 8-bit mask ----
__global__ void build_table(const float* __restrict__ emb,
                            const float* __restrict__ mask,
                            unsigned short* __restrict__ T, int N) {
    int n = blockIdx.x * blockDim.x + threadIdx.x;
    if (n >= N) return;
    const float4* p = (const float4*)(emb + (size_t)n * NTD);
    float4 lo = p[0], hi = p[1];
    float ev[8] = {lo.x, lo.y, lo.z, lo.w, hi.x, hi.y, hi.z, hi.w};
    float mf = mask[n] * 255.0f + 0.5f;
    unsigned m8 = (unsigned)mf; if (m8 > 255u) m8 = 255u;
    unsigned short row[8];
    #pragma unroll
    for (int j = 0; j < 8; ++j)
        row[j] = pack_emb(ev[j], (m8 >> j) & 1u);
    int4 out;
    out.x = (int)((unsigned)row[0] | ((unsigned)row[1] << 16));
    out.y = (int)((unsigned)row[2] | ((unsigned)row[3] << 16));
    out.z = (int)((unsigned)row[4] | ((unsigned)row[5] << 16));
    out.w = (int)((unsigned)row[6] | ((unsigned)row[7] << 16));
    *(int4*)(T + (size_t)n * 8) = out;
}

// decode the 8-bit mask from the 8 LSBs of a row
__device__ __forceinline__ unsigned decode_m8(int4 r) {
    unsigned m;
    m  = ((unsigned)r.x & 1u);
    m |= (((unsigned)r.x >> 16) & 1u) << 1;
    m |= ((unsigned)r.y & 1u) << 2;
    m |= (((unsigned)r.y >> 16) & 1u) << 3;
    m |= ((unsigned)r.z & 1u) << 4;
    m |= (((unsigned)r.z >> 16) & 1u) << 5;
    m |= ((unsigned)r.w & 1u) << 6;
    m |= (((unsigned)r.w >> 16) & 1u) << 7;
    return m;
}

// ---------------- main kernel (32x32x16 MFMA, 64 edges / iteration) ----------------
// Lane c (<32) owns the 16B s-row of edge c; lane 32+c owns the 16B d-row of edge c.
// ONE dwordx4 per node reference -> 2 divergent lookups per edge (structural minimum).
// MFMA1 (A_s): k0-7 = W1 rows 0-7 (emb_s), k8 = W1 row 16 (mask_s), k9 = b1.
//   B1: h=0 lanes -> own row;  h=1 lanes -> [ms, 1.0, 0...]  (ms via shfl_xor32 of m8)
// MFMA2 (A_d): k0 = W1 row 17 (mask_d), k8-15 = W1 rows 8-15 (emb_d).
//   B2: h=0 lanes -> [md, 0...];  h=1 lanes -> own row.

template <int ESZ>
__device__ __forceinline__ uint2 ld_idx2(const char* __restrict__ idxBase,
                                         unsigned grp, unsigned nGroups,
                                         unsigned E, unsigned cc) {
    unsigned g = grp < nGroups ? grp : nGroups - 1u;   // clamp (prefetch safety)
    unsigned eA = g * 64u + cc;
    unsigned eB = eA + 32u;
    if (eA >= E) eA = E - 1u;
    if (eB >= E) eB = E - 1u;
    uint2 r;
    r.x = *(const unsigned*)(idxBase + (size_t)eA * ESZ);
    r.y = *(const unsigned*)(idxBase + (size_t)eB * ESZ);
    return r;
}

__device__ __forceinline__ int4 grow(const char* __restrict__ Tc, unsigned idx) {
    return *(const int4*)(Tc + (size_t)idx * 16u);
}

// build B-fragments for one 32-edge tile from this lane's row
__device__ __forceinline__ void tile_frags(int4 row, int h, short8& fb1, short8& fb2) {
    unsigned m8 = decode_m8(row);
    unsigned m8p = (unsigned)__shfl_xor((int)m8, 32, 64);   // partner's mask bits
    float mfv = (float)m8p * (1.0f / 255.0f);
    unsigned mbf = (unsigned)(unsigned short)f2bf(mfv);
    int4 b1i, b2i;
    if (h) {
        b1i.x = (int)(mbf | 0x3F800000u);  // low short = ms (k8), high short = 1.0 (k9)
        b1i.y = 0; b1i.z = 0; b1i.w = 0;
        b2i = row;                          // k8-15 = emb_d
    } else {
        b1i = row;                          // k0-7 = emb_s
        b2i.x = (int)mbf;                   // low short = md (k0)
        b2i.y = 0; b2i.z = 0; b2i.w = 0;
    }
    fb1 = __builtin_bit_cast(short8, b1i);
    fb2 = __builtin_bit_cast(short8, b2i);
}

template <int ESZ>
__device__ void run32(const char* __restrict__ ei,
                      const char* __restrict__ Tc,
                      float* __restrict__ out, unsigned E,
                      short8 as, short8 ad, const float* __restrict__ w2r, float bias2,
                      unsigned waveId, unsigned nWaves, int h, int c, int lane) {
    const unsigned nGroups = (E + 63u) >> 6;
    // lanes<32 read the s-index stream, lanes>=32 the d-index stream
    const char* idxBase = ei + (h ? (size_t)E * ESZ : 0);
    const unsigned cc = (unsigned)c;

    if (waveId >= nGroups) return;
    unsigned cur = waveId;

    // prologue: rows for cur; indices for cur+W
    uint2 i0 = ld_idx2<ESZ>(idxBase, cur, nGroups, E, cc);
    int4 rA = grow(Tc, i0.x);
    int4 rB = grow(Tc, i0.y);
    uint2 i1 = ld_idx2<ESZ>(idxBase, cur + nWaves, nGroups, E, cc);

    while (true) {
        // prefetch: next group's rows + next-next indices (overlap with compute)
        int4 nA = grow(Tc, i1.x);
        int4 nB = grow(Tc, i1.y);
        uint2 i2 = ld_idx2<ESZ>(idxBase, cur + 2u * nWaves, nGroups, E, cc);

        // fragments
        short8 fb1A, fb2A, fb1B, fb2B;
        tile_frags(rA, h, fb1A, fb2A);
        tile_frags(rB, h, fb1B, fb2B);

        // layer 1: two 32-edge tiles, 2 MFMAs each
        floatx16 accA = {0.f,0.f,0.f,0.f,0.f,0.f,0.f,0.f,0.f,0.f,0.f,0.f,0.f,0.f,0.f,0.f};
        floatx16 accB = accA;
        accA = __builtin_amdgcn_mfma_f32_32x32x16_bf16(as, fb1A, accA, 0, 0, 0);
        accB = __builtin_amdgcn_mfma_f32_32x32x16_bf16(as, fb1B, accB, 0, 0, 0);
        accA = __builtin_amdgcn_mfma_f32_32x32x16_bf16(ad, fb2A, accA, 0, 0, 0);
        accB = __builtin_amdgcn_mfma_f32_32x32x16_bf16(ad, fb2B, accB, 0, 0, 0);

        // layer 2: lane(h,c) holds H rows (q&3)+8*(q>>2)+4h of its edge
        float pA0 = 0.f, pA1 = 0.f, pB0 = 0.f, pB1 = 0.f;
        #pragma unroll
        for (int q = 0; q < 16; q += 2) {
            pA0 += fmaxf(accA[q],     0.f) * w2r[q];
            pA1 += fmaxf(accA[q + 1], 0.f) * w2r[q + 1];
            pB0 += fmaxf(accB[q],     0.f) * w2r[q];
            pB1 += fmaxf(accB[q + 1], 0.f) * w2r[q + 1];
        }
        float pA = pA0 + pA1;
        float pB = pB0 + pB1;
        pA += __shfl_xor(pA, 32, 64);   // combine the two h-halves
        pB += __shfl_xor(pB, 32, 64);
        float vA = fast_sigmoid(pA + bias2);
        float vB = fast_sigmoid(pB + bias2);

        // lane l stores edge base64 + l
        float v = (h == 0) ? vA : vB;
        unsigned e = (cur << 6) + (unsigned)lane;
        if (e < E) out[e] = v;

        cur += nWaves;
        if (cur >= nGroups) break;
        rA = nA; rB = nB;
        i1 = i2;
    }
}

__global__ __launch_bounds__(256, 4) void lg_table_kernel(
    const char* __restrict__ ei_bytes,
    const unsigned short* __restrict__ T,
    const float* __restrict__ W1,
    const float* __restrict__ b1,
    const float* __restrict__ W2,
    const float* __restrict__ b2,
    float* __restrict__ out,
    long long E)
{
    const int lane = threadIdx.x & 63;
    const int waveInBlock = threadIdx.x >> 6;
    const unsigned waveId = (unsigned)(blockIdx.x * (blockDim.x >> 6) + waveInBlock);
    const unsigned nWaves = (unsigned)(gridDim.x * (blockDim.x >> 6));

    // detect edge_index element size: int64 (odd 4B words all zero) vs int32
    const int* ei32 = (const int*)ei_bytes;
    int probe = ei32[2 * lane + 1];
    unsigned long long nz = __ballot(probe != 0);
    const int esz = (nz == 0ull) ? 8 : 4;

    const int c = lane & 31;   // B col / A row index
    const int h = lane >> 5;   // k-half: k = 8h + j

    // A_s: h=0: k=j -> W1 rows 0-7 (emb_s);  h=1: k=8+j -> j0: W1 row 16 (ms), j1: b1
    // A_d: h=0: k=j -> j0: W1 row 17 (md);   h=1: k=8+j -> W1 rows 8-15 (emb_d)
    short8 as, ad;
    #pragma unroll
    for (int j = 0; j < 8; ++j) {
        float vs = 0.f, vd = 0.f;
        if (h == 0) {
            vs = W1[j * HID + c];
            if (j == 0) vd = W1[17 * HID + c];
        } else {
            if (j == 0) vs = W1[16 * HID + c];
            else if (j == 1) vs = b1[c];
            vd = W1[(8 + j) * HID + c];
        }
        as[j] = f2bf(vs);
        ad[j] = f2bf(vd);
    }

    // W2 for the 16 H-rows this lane's acc regs hold: row(q) = (q&3) + 8*(q>>2) + 4h
    float w2r[16];
    #pragma unroll
    for (int q = 0; q < 16; ++q)
        w2r[q] = W2[(q & 3) + 8 * (q >> 2) + 4 * h];

    const float bias2 = b2[0];

    if (esz == 8)
        run32<8>(ei_bytes, (const char*)T, out, (unsigned)E, as, ad, w2r, bias2,
                 waveId, nWaves, h, c, lane);
    else
        run32<4>(ei_bytes, (const char*)T, out, (unsigned)E, as, ad, w2r, bias2,
                 waveId, nWaves, h, c, lane);
}

// ---------------- fallback (round-1 kernel, used if d_ws too small) ----------------
__global__ __launch_bounds__(256, 4) void lg_kernel(
    const float* __restrict__ nt_emb,
    const char* __restrict__ ei_bytes,
    const float* __restrict__ lm_mask,
    const float* __restrict__ W1,
    const float* __restrict__ b1,
    const float* __restrict__ W2,
    const float* __restrict__ b2,
    float* __restrict__ out,
    long long E)
{
    const int lane = threadIdx.x & 63;
    const int waveInBlock = threadIdx.x >> 6;
    const long long waveId = (long long)blockIdx.x * (blockDim.x >> 6) + waveInBlock;
    const long long nWaves = (long long)gridDim.x * (blockDim.x >> 6);

    const int* ei32 = (const int*)ei_bytes;
    int probe = ei32[2 * lane + 1];
    unsigned long long nz = __ballot(probe != 0);
    const long long esz = (nz == 0ull) ? 8 : 4;

    const int r = lane & 15;
    const int g = lane >> 4;

    short8 a0, a1;
    #pragma unroll
    for (int j = 0; j < 8; ++j) {
        int k = g * 8 + j;
        float v0 = 0.f, v1 = 0.f;
        if (k < FAN_IN)       { v0 = W1[k * HID + r];      v1 = W1[k * HID + 16 + r]; }
        else if (k == FAN_IN) { v0 = b1[r];                v1 = b1[16 + r]; }
        a0[j] = f2bf(v0);
        a1[j] = f2bf(v1);
    }

    float w2v0[4], w2v1[4];
    #pragma unroll
    for (int q = 0; q < 4; ++q) {
        w2v0[q] = W2[g * 4 + q];
        w2v1[q] = W2[16 + g * 4 + q];
    }
    const float bias2 = b2[0];

    const long long nGroups = (E + 15) >> 4;
    for (long long grp = waveId; grp < nGroups; grp += nWaves) {
        long long e = (grp << 4) + r;
        const bool valid = (e < E);
        long long ec = valid ? e : (E - 1);

        int s = *(const int*)(ei_bytes + ec * esz);
        int d = *(const int*)(ei_bytes + (E + ec) * esz);

        short8 fb;
        #pragma unroll
        for (int j = 0; j < 8; ++j) fb[j] = 0;
        if (g < 2) {
            const float4* p = (const float4*)(nt_emb + (long long)(g == 0 ? s : d) * NTD);
            float4 lo = p[0];
            float4 hi = p[1];
            fb[0] = f2bf(lo.x); fb[1] = f2bf(lo.y); fb[2] = f2bf(lo.z); fb[3] = f2bf(lo.w);
            fb[4] = f2bf(hi.x); fb[5] = f2bf(hi.y); fb[6] = f2bf(hi.z); fb[7] = f2bf(hi.w);
        } else if (g == 2) {
            fb[0] = f2bf(lm_mask[s]);
            fb[1] = f2bf(lm_mask[d]);
            fb[2] = (short)0x3F80;
        }

        floatx4 acc0 = {0.f, 0.f, 0.f, 0.f};
        floatx4 acc1 = {0.f, 0.f, 0.f, 0.f};
        acc0 = __builtin_amdgcn_mfma_f32_16x16x32_bf16(a0, fb, acc0, 0, 0, 0);
        acc1 = __builtin_amdgcn_mfma_f32_16x16x32_bf16(a1, fb, acc1, 0, 0, 0);

        float partial = 0.f;
        #pragma unroll
        for (int q = 0; q < 4; ++q) {
            partial += fmaxf(acc0[q], 0.f) * w2v0[q];
            partial += fmaxf(acc1[q], 0.f) * w2v1[q];
        }
        partial += __shfl_xor(partial, 16, 64);
        partial += __shfl_xor(partial, 32, 64);

        float val = fast_sigmoid(partial + bias2);
        if (g == 0 && valid) out[e] = val;
    }
}

extern "C" void kernel_launch(void* const* d_in, const int* in_sizes, int n_in,
                              void* d_out, int out_size, void* d_ws, size_t ws_size,
                              hipStream_t stream) {
    const float* nt_emb = (const float*)d_in[0];
    const char*  ei     = (const char*)d_in[1];
    const float* lm     = (const float*)d_in[2];
    const float* W1     = (const float*)d_in[3];
    const float* b1     = (const float*)d_in[4];
    const float* W2     = (const float*)d_in[5];
    const float* b2     = (const float*)d_in[6];
    float* out = (float*)d_out;

    long long E = (long long)in_sizes[1] / 2;   // edge_index is [2, E]
    int N = in_sizes[2];                        // lm_mask is [N]

    size_t tableBytes = (size_t)N * 16;
    if (ws_size >= tableBytes) {
        unsigned short* T = (unsigned short*)d_ws;
        build_table<<<dim3((N + 255) / 256), dim3(256), 0, stream>>>(nt_emb, lm, T, N);
        lg_table_kernel<<<dim3(2048), dim3(256), 0, stream>>>(ei, T, W1, b1, W2, b2, out, E);
    } else {
        lg_kernel<<<dim3(2048), dim3(256), 0, stream>>>(nt_emb, ei, lm, W1, b1, W2, b2, out, E);
    }
}